// Round 5
// baseline (130.624 us; speedup 1.0000x reference)
//
#include <hip/hip_runtime.h>
#include <stdint.h>

#define L_DIM 16384
#define H_DIM 512
#define P_DIM 512
#define T_CH  32
#define NC    (L_DIM / T_CH)      // 512 chunks
#define LP    ((size_t)L_DIM * P_DIM)
#define LH    ((size_t)L_DIM * H_DIM)

typedef unsigned short u16;
typedef __attribute__((ext_vector_type(8))) _Float16 f16x8;  // 8 fp16 = 4 VGPRs
typedef __attribute__((ext_vector_type(4))) float f32x4;
typedef __attribute__((ext_vector_type(8))) unsigned short u16x8;

// ---- fp16 helpers ----------------------------------------------------------
__device__ __forceinline__ u16 f2h(float x) {
    _Float16 h = (_Float16)x;            // RTNE
    return __builtin_bit_cast(u16, h);
}
__device__ __forceinline__ float h2f(u16 h) {
    return (float)__builtin_bit_cast(_Float16, h);
}

// ---- async global->LDS, 16B per lane, wave-uniform LDS base ----------------
__device__ __forceinline__ void gload16(const void* g, void* lds) {
    __builtin_amdgcn_global_load_lds(
        (const __attribute__((address_space(1))) void*)g,
        (__attribute__((address_space(3))) void*)(uintptr_t)lds,
        16, 0, 0);
}

__device__ __forceinline__ f32x4 mfma_f16(f16x8 a, f16x8 b, f32x4 c) {
    return __builtin_amdgcn_mfma_f32_16x16x32_f16(a, b, c, 0, 0, 0);
}

// ---------------------------------------------------------------------------
// prep: ZOH discretization. lambda_bar, power table lambda^k (k=0..32),
// gamma=(lb-1)/Lambda.
// ---------------------------------------------------------------------------
__global__ __launch_bounds__(P_DIM) void prep_kernel(
    const float* __restrict__ Lre, const float* __restrict__ Lim,
    const float* __restrict__ log_step,
    float* __restrict__ lbr, float* __restrict__ lbi,
    float* __restrict__ gre, float* __restrict__ gim,
    float* __restrict__ powr, float* __restrict__ powi)
{
    int p = threadIdx.x;
    float st = expf(log_step[p]);
    float ar = Lre[p] * st, ai = Lim[p] * st;
    float er = expf(ar);
    float lr = er * cosf(ai), li = er * sinf(ai);
    lbr[p] = lr; lbi[p] = li;
    float den = Lre[p] * Lre[p] + Lim[p] * Lim[p];
    float x = lr - 1.0f, y = li;
    gre[p] = (x * Lre[p] + y * Lim[p]) / den;
    gim[p] = (y * Lre[p] - x * Lim[p]) / den;
    float pr = 1.f, pi2 = 0.f;
    powr[p] = 1.f; powi[p] = 0.f;
    for (int k = 1; k <= T_CH; ++k) {
        float nr = pr * lr - pi2 * li;
        float ni = pr * li + pi2 * lr;
        pr = nr; pi2 = ni;
        powr[(size_t)k * P_DIM + p] = pr;
        powi[(size_t)k * P_DIM + p] = pi2;
    }
}

// ---------------------------------------------------------------------------
// convert u (L,H) fp32 -> fp16, 8 elems/thread
// ---------------------------------------------------------------------------
__global__ __launch_bounds__(256) void convert_u(
    const float* __restrict__ u, u16* __restrict__ uh)
{
    size_t i = ((size_t)blockIdx.x * 256 + threadIdx.x) * 8;
    float4 v0 = *(const float4*)(u + i);
    float4 v1 = *(const float4*)(u + i + 4);
    u16x8 h;
    h[0] = f2h(v0.x); h[1] = f2h(v0.y); h[2] = f2h(v0.z); h[3] = f2h(v0.w);
    h[4] = f2h(v1.x); h[5] = f2h(v1.y); h[6] = f2h(v1.z); h[7] = f2h(v1.w);
    *(u16x8*)(uh + i) = h;
}

// ---------------------------------------------------------------------------
// Bcat (1024 x 512) fp16: rows 0..511 = Re(gamma*B), rows 512..1023 = Im.
// ---------------------------------------------------------------------------
__global__ __launch_bounds__(256) void build_bcat(
    const float* __restrict__ Bre, const float* __restrict__ Bim,
    const float* __restrict__ gre, const float* __restrict__ gim,
    u16* __restrict__ Bcat)
{
    int idx = blockIdx.x * 256 + threadIdx.x;   // p*H + h
    int p = idx >> 9, h = idx & 511;
    float br = Bre[idx], bi = Bim[idx];
    float gr = gre[p], gi = gim[p];
    Bcat[(size_t)p * 512 + h]         = f2h(gr * br - gi * bi);
    Bcat[(size_t)(512 + p) * 512 + h] = f2h(gr * bi + gi * br);
}

// ---------------------------------------------------------------------------
// Ccat (512 x 1024) fp16: row h = [Cre[h][:] | -Cim[h][:]]
// ---------------------------------------------------------------------------
__global__ __launch_bounds__(256) void build_ccat(
    const float* __restrict__ Cre, const float* __restrict__ Cim,
    u16* __restrict__ Ccat)
{
    int idx = blockIdx.x * 256 + threadIdx.x;   // h*P + p
    int h = idx >> 9, p = idx & 511;
    size_t row = (size_t)h * 1024;
    Ccat[row + p]       = f2h(Cre[idx]);
    Ccat[row + 512 + p] = f2h(-Cim[idx]);
}

// ---------------------------------------------------------------------------
// MFMA GEMM, 128x128 tile, BK=64, 4 waves (each 64x64), global_load_lds
// staging, XOR-swizzled source / ds_read pair.
// MODE 0 (Bu GEMM): writes Bu fp16 (re|im split at col 512) AND fused
//   weighted chunk-sum partials from the fp32 accumulators:
//   Rwr[c][p]=sum_k wr*Bu_re, Rwi=sum_k wi*Bu_re (re-cols);
//   Iwr/Iwi likewise from im-cols; w_k = lambda_p^(31-k).
// MODE 1 (y GEMM): out fp32 = acc + D[col]*uh[row,col].
// __launch_bounds__(256,2): 256-reg budget. (256,4) caps at 128 and SPILLS —
// round-3 regression: +183MB scratch writes/dispatch, GEMM 64->118us.
// ---------------------------------------------------------------------------
template<int KTOT, int NBN, int MODE>
__global__ __launch_bounds__(256, 2) void gemm_mfma(
    const u16* __restrict__ A0, const u16* __restrict__ A1,
    const u16* __restrict__ Bmat,
    void* __restrict__ O0v, void* __restrict__ O1v,
    const float* __restrict__ Dvec, const u16* __restrict__ uIn,
    const float* __restrict__ powr, const float* __restrict__ powi,
    float* __restrict__ Rwr, float* __restrict__ Rwi,
    float* __restrict__ Iwr, float* __restrict__ Iwi)
{
    __shared__ u16 Als[128 * 64];
    __shared__ u16 Bls[128 * 64];

    const u16* Aseg[2] = {A0, A1};

    // XCD-chunked block mapping: same-M blocks land on the same XCD (b%8).
    int b = blockIdx.x;
    int m = (b & 7) * 16 + b / (8 * NBN);
    int n = (b >> 3) & (NBN - 1);
    int m0 = m * 128, n0 = n * 128;

    int tid = threadIdx.x;
    int w = tid >> 6, lane = tid & 63;
    int wm = w >> 1, wn = w & 1;

    f32x4 acc[4][4];
    #pragma unroll
    for (int i = 0; i < 4; ++i)
        #pragma unroll
        for (int j = 0; j < 4; ++j) acc[i][j] = (f32x4)0.f;

    int lr8  = lane >> 3;   // 0..7
    int slin = lane & 7;    // linear 16B slot this lane writes

    char* AlsB = (char*)&Als[0];
    char* BlsB = (char*)&Bls[0];

    const int NSEG = KTOT / 512;
    #pragma unroll
    for (int seg = 0; seg < NSEG; ++seg) {
        const u16* Ap = Aseg[seg];
        for (int k8 = 0; k8 < 8; ++k8) {
            int ko = k8 * 64;           // K offset within segment (elements)
            int kB = seg * 512 + ko;    // K offset within full KTOT (for B)

            __syncthreads();            // previous tile fully consumed
            #pragma unroll
            for (int c = 0; c < 4; ++c) {
                int sidx = w * 4 + c;           // 16 wave-issues cover 16KB
                int r = sidx * 8 + lr8;         // tile row this lane feeds
                int g = slin ^ (r & 7);         // pre-swizzled source slot
                const u16* ga = Ap + (size_t)(m0 + r) * 512 + ko + g * 8;
                gload16(ga, AlsB + sidx * 1024);
                const u16* gb = Bmat + (size_t)(n0 + r) * KTOT + kB + g * 8;
                gload16(gb, BlsB + sidx * 1024);
            }
            asm volatile("s_waitcnt vmcnt(0)" ::: "memory");
            __syncthreads();            // staged tile visible

            f16x8 a[4][2], bf[4][2];
            #pragma unroll
            for (int mm = 0; mm < 4; ++mm)
                #pragma unroll
                for (int kk = 0; kk < 2; ++kk) {
                    int row = wm * 64 + mm * 16 + (lane & 15);
                    int sl  = kk * 4 + (lane >> 4);
                    int off = row * 128 + ((sl ^ (lane & 7)) << 4);
                    a[mm][kk] = *(const f16x8*)(AlsB + off);
                }
            #pragma unroll
            for (int nn = 0; nn < 4; ++nn)
                #pragma unroll
                for (int kk = 0; kk < 2; ++kk) {
                    int row = wn * 64 + nn * 16 + (lane & 15);
                    int sl  = kk * 4 + (lane >> 4);
                    int off = row * 128 + ((sl ^ (lane & 7)) << 4);
                    bf[nn][kk] = *(const f16x8*)(BlsB + off);
                }
            #pragma unroll
            for (int mm = 0; mm < 4; ++mm)
                #pragma unroll
                for (int nn = 0; nn < 4; ++nn) {
                    acc[mm][nn] = mfma_f16(a[mm][0], bf[nn][0], acc[mm][nn]);
                    acc[mm][nn] = mfma_f16(a[mm][1], bf[nn][1], acc[mm][nn]);
                }
        }
    }

    // epilogue: C/D layout col = lane&15, row = (lane>>4)*4 + reg  [m89]
    int colb = n0 + wn * 64;
    int rowb = m0 + wm * 64;
    #pragma unroll
    for (int mm = 0; mm < 4; ++mm)
        #pragma unroll
        for (int nn = 0; nn < 4; ++nn) {
            f32x4 v = acc[mm][nn];
            int col = colb + nn * 16 + (lane & 15);
            #pragma unroll
            for (int j = 0; j < 4; ++j) {
                int row = rowb + mm * 16 + (lane >> 4) * 4 + j;
                if constexpr (MODE == 0) {
                    size_t oidx = (size_t)row * 512 + (col & 511);
                    u16 hv = f2h(v[j]);
                    if (col < 512) ((u16*)O0v)[oidx] = hv;
                    else           ((u16*)O1v)[oidx] = hv;
                } else {
                    size_t oidx = (size_t)row * 512 + col;
                    ((float*)O0v)[oidx] = v[j] + Dvec[col] * h2f(uIn[oidx]);
                }
            }
        }

    if constexpr (MODE == 0) {
        // fused weighted chunk sums: each wm-half holds 2 full chunks of 32.
        float swr[2][4] = {{0.f}};
        float swi[2][4] = {{0.f}};
        #pragma unroll
        for (int mm = 0; mm < 4; ++mm) {
            int ch = mm >> 1;                      // chunk within wm-half
            #pragma unroll
            for (int nn = 0; nn < 4; ++nn) {
                int col = colb + nn * 16 + (lane & 15);
                int p = col & 511;
                f32x4 v = acc[mm][nn];
                #pragma unroll
                for (int j = 0; j < 4; ++j) {
                    int k = (mm & 1) * 16 + (lane >> 4) * 4 + j;   // 0..31
                    int e = (T_CH - 1) - k;
                    float wr = powr[(size_t)e * 512 + p];
                    float wi = powi[(size_t)e * 512 + p];
                    swr[ch][nn] = fmaf(wr, v[j], swr[ch][nn]);
                    swi[ch][nn] = fmaf(wi, v[j], swi[ch][nn]);
                }
            }
        }
        #pragma unroll
        for (int ch = 0; ch < 2; ++ch)
            #pragma unroll
            for (int nn = 0; nn < 4; ++nn) {
                float a2 = swr[ch][nn];
                a2 += __shfl_xor(a2, 16); a2 += __shfl_xor(a2, 32);
                swr[ch][nn] = a2;
                float b2 = swi[ch][nn];
                b2 += __shfl_xor(b2, 16); b2 += __shfl_xor(b2, 32);
                swi[ch][nn] = b2;
            }
        if (lane < 16) {
            #pragma unroll
            for (int ch = 0; ch < 2; ++ch) {
                int c = (m0 >> 5) + wm * 2 + ch;   // global chunk index
                #pragma unroll
                for (int nn = 0; nn < 4; ++nn) {
                    int col = colb + nn * 16 + lane;
                    int p = col & 511;
                    size_t pidx = (size_t)c * 512 + p;
                    if (col < 512) { Rwr[pidx] = swr[ch][nn]; Rwi[pidx] = swi[ch][nn]; }
                    else           { Iwr[pidx] = swr[ch][nn]; Iwi[pidx] = swi[ch][nn]; }
                }
            }
        }
    }
}

// ---------------------------------------------------------------------------
// scan chunks: exclusive scan across 512 chunk aggregates with factor
// lambda^32. Combines the 4 gemm partials on the fly:
//   s_re = Rwr - Iwi ; s_im = Rwi + Iwr.
// 8 blocks x 64 threads so L2 traffic isn't funneled through one CU
// (round-4: 1-block version was ~13us on ~2MB).
// ---------------------------------------------------------------------------
__global__ __launch_bounds__(64) void scan_chunks(
    const float* __restrict__ Rwr, const float* __restrict__ Rwi,
    const float* __restrict__ Iwr, const float* __restrict__ Iwi,
    const float* __restrict__ powr, const float* __restrict__ powi,
    float* __restrict__ carr, float* __restrict__ cari)
{
    int p = blockIdx.x * 64 + threadIdx.x;
    float ar = powr[(size_t)T_CH * P_DIM + p];   // lambda^32
    float ai = powi[(size_t)T_CH * P_DIM + p];
    float sr = 0.f, si = 0.f;
    #pragma unroll 8
    for (int c = 0; c < NC; ++c) {
        size_t idx = (size_t)c * P_DIM + p;
        carr[idx] = sr; cari[idx] = si;
        float vre = Rwr[idx] - Iwi[idx];
        float vim = Rwi[idx] + Iwr[idx];
        float nr = fmaf(ar, sr, fmaf(-ai, si, vre));
        float ni = fmaf(ar, si, fmaf( ai, sr, vim));
        sr = nr; si = ni;
    }
}

// ---------------------------------------------------------------------------
// scan fix: local recurrence seeded with carry; emit x as fp16.
// T=32: 512 blocks -> 2 blocks/CU, serial depth halved vs T=64.
// ---------------------------------------------------------------------------
__global__ __launch_bounds__(P_DIM) void scan_fix(
    const u16* __restrict__ burh, const u16* __restrict__ buih,
    const float* __restrict__ lbr, const float* __restrict__ lbi,
    const float* __restrict__ carr, const float* __restrict__ cari,
    u16* __restrict__ xrh, u16* __restrict__ xih)
{
    int p = threadIdx.x;
    int c = blockIdx.x;
    float lr = lbr[p], li = lbi[p];
    float xr = carr[(size_t)c * P_DIM + p];
    float xi = cari[(size_t)c * P_DIM + p];
    size_t base = (size_t)c * T_CH * P_DIM + p;
    #pragma unroll 4
    for (int k = 0; k < T_CH; ++k) {
        size_t idx = base + (size_t)k * P_DIM;
        float br = h2f(burh[idx]), bi = h2f(buih[idx]);
        float nr = fmaf(lr, xr, fmaf(-li, xi, br));
        float ni = fmaf(lr, xi, fmaf( li, xr, bi));
        xr = nr; xi = ni;
        xrh[idx] = f2h(xr);
        xih[idx] = f2h(xi);
    }
}

// ---------------------------------------------------------------------------
extern "C" void kernel_launch(void* const* d_in, const int* in_sizes, int n_in,
                              void* d_out, int out_size, void* d_ws, size_t ws_size,
                              hipStream_t stream)
{
    const float* u        = (const float*)d_in[0];
    const float* Lre      = (const float*)d_in[1];
    const float* Lim      = (const float*)d_in[2];
    const float* Bre      = (const float*)d_in[3];
    const float* Bim      = (const float*)d_in[4];
    const float* Cre      = (const float*)d_in[5];
    const float* Cim      = (const float*)d_in[6];
    const float* D        = (const float*)d_in[7];
    const float* log_step = (const float*)d_in[8];
    float* out = (float*)d_out;

    // workspace layout (bytes)
    char* w8 = (char*)d_ws;
    u16*   burh = (u16*)(w8);                                // 16 MB
    u16*   buih = (u16*)(w8 + 16777216);                     // 16 MB
    u16*   xrh  = (u16*)(w8 + 33554432);                     // 16 MB
    u16*   xih  = (u16*)(w8 + 50331648);                     // 16 MB
    u16*   uh   = (u16*)(w8 + 67108864);                     // 16 MB
    u16*   Bcat = (u16*)(w8 + 83886080);                     // 1 MB
    u16*   Ccat = (u16*)(w8 + 84934656);                     // 1 MB
    float* Rwr  = (float*)(w8 + 85983232);                   // 1 MB (NC*P fp32)
    float* Rwi  = (float*)(w8 + 87031808);
    float* Iwr  = (float*)(w8 + 88080384);
    float* Iwi  = (float*)(w8 + 89128960);
    float* carr = (float*)(w8 + 90177536);                   // 1 MB
    float* cari = (float*)(w8 + 91226112);
    float* powr = (float*)(w8 + 92274688);                   // 33*512*4
    float* powi = (float*)(w8 + 92342272);
    float* lbr  = (float*)(w8 + 92409856);                   // small
    float* lbi  = lbr + P_DIM;
    float* gre  = lbi + P_DIM;
    float* gim  = gre + P_DIM;

    prep_kernel<<<1, P_DIM, 0, stream>>>(Lre, Lim, log_step, lbr, lbi, gre, gim, powr, powi);
    convert_u<<<(int)(LH / 2048), 256, 0, stream>>>(u, uh);
    build_bcat<<<(P_DIM * H_DIM) / 256, 256, 0, stream>>>(Bre, Bim, gre, gim, Bcat);
    build_ccat<<<(H_DIM * P_DIM) / 256, 256, 0, stream>>>(Cre, Cim, Ccat);

    // Bu GEMM (+fused chunk-sum partials): A = uh, B = Bcat (1024 x 512)
    gemm_mfma<512, 8, 0><<<1024, 256, 0, stream>>>(
        uh, uh, Bcat, burh, buih, nullptr, nullptr,
        powr, powi, Rwr, Rwi, Iwr, Iwi);

    scan_chunks<<<8, 64, 0, stream>>>(Rwr, Rwi, Iwr, Iwi, powr, powi, carr, cari);
    scan_fix<<<NC, P_DIM, 0, stream>>>(burh, buih, lbr, lbi, carr, cari, xrh, xih);

    // y GEMM: A segs [xr | xi] (fp16), B = Ccat (512 x 1024) -> out (+D*uh)
    gemm_mfma<1024, 4, 1><<<512, 256, 0, stream>>>(
        xrh, xih, Ccat, out, nullptr, D, uh,
        nullptr, nullptr, nullptr, nullptr, nullptr, nullptr);
}

// Round 6
// 130.573 us; speedup vs baseline: 1.0004x; 1.0004x over previous
//
#include <hip/hip_runtime.h>
#include <stdint.h>

#define L_DIM 16384
#define H_DIM 512
#define P_DIM 512
#define T_CH  32
#define NC    (L_DIM / T_CH)      // 512 chunks
#define LP    ((size_t)L_DIM * P_DIM)
#define LH    ((size_t)L_DIM * H_DIM)

typedef unsigned short u16;
typedef __attribute__((ext_vector_type(8))) _Float16 f16x8;  // 8 fp16 = 4 VGPRs
typedef __attribute__((ext_vector_type(4))) float f32x4;
typedef __attribute__((ext_vector_type(8))) unsigned short u16x8;

// ---- fp16 helpers ----------------------------------------------------------
__device__ __forceinline__ u16 f2h(float x) {
    _Float16 h = (_Float16)x;            // RTNE
    return __builtin_bit_cast(u16, h);
}
__device__ __forceinline__ float h2f(u16 h) {
    return (float)__builtin_bit_cast(_Float16, h);
}

// ---- async global->LDS, 16B per lane, wave-uniform LDS base ----------------
__device__ __forceinline__ void gload16(const void* g, void* lds) {
    __builtin_amdgcn_global_load_lds(
        (const __attribute__((address_space(1))) void*)g,
        (__attribute__((address_space(3))) void*)(uintptr_t)lds,
        16, 0, 0);
}

__device__ __forceinline__ f32x4 mfma_f16(f16x8 a, f16x8 b, f32x4 c) {
    return __builtin_amdgcn_mfma_f32_16x16x32_f16(a, b, c, 0, 0, 0);
}

// ---------------------------------------------------------------------------
// prep: ZOH discretization. lambda_bar, power table lambda^k (k=0..32),
// gamma=(lb-1)/Lambda.
// ---------------------------------------------------------------------------
__global__ __launch_bounds__(P_DIM) void prep_kernel(
    const float* __restrict__ Lre, const float* __restrict__ Lim,
    const float* __restrict__ log_step,
    float* __restrict__ lbr, float* __restrict__ lbi,
    float* __restrict__ gre, float* __restrict__ gim,
    float* __restrict__ powr, float* __restrict__ powi)
{
    int p = threadIdx.x;
    float st = expf(log_step[p]);
    float ar = Lre[p] * st, ai = Lim[p] * st;
    float er = expf(ar);
    float lr = er * cosf(ai), li = er * sinf(ai);
    lbr[p] = lr; lbi[p] = li;
    float den = Lre[p] * Lre[p] + Lim[p] * Lim[p];
    float x = lr - 1.0f, y = li;
    gre[p] = (x * Lre[p] + y * Lim[p]) / den;
    gim[p] = (y * Lre[p] - x * Lim[p]) / den;
    float pr = 1.f, pi2 = 0.f;
    powr[p] = 1.f; powi[p] = 0.f;
    for (int k = 1; k <= T_CH; ++k) {
        float nr = pr * lr - pi2 * li;
        float ni = pr * li + pi2 * lr;
        pr = nr; pi2 = ni;
        powr[(size_t)k * P_DIM + p] = pr;
        powi[(size_t)k * P_DIM + p] = pi2;
    }
}

// ---------------------------------------------------------------------------
// convert u (L,H) fp32 -> fp16, 8 elems/thread
// ---------------------------------------------------------------------------
__global__ __launch_bounds__(256) void convert_u(
    const float* __restrict__ u, u16* __restrict__ uh)
{
    size_t i = ((size_t)blockIdx.x * 256 + threadIdx.x) * 8;
    float4 v0 = *(const float4*)(u + i);
    float4 v1 = *(const float4*)(u + i + 4);
    u16x8 h;
    h[0] = f2h(v0.x); h[1] = f2h(v0.y); h[2] = f2h(v0.z); h[3] = f2h(v0.w);
    h[4] = f2h(v1.x); h[5] = f2h(v1.y); h[6] = f2h(v1.z); h[7] = f2h(v1.w);
    *(u16x8*)(uh + i) = h;
}

// ---------------------------------------------------------------------------
// merged build: blocks 0..1023 -> Bcat (1024 x 512) fp16
//               blocks 1024..2047 -> Ccat (512 x 1024) fp16
// ---------------------------------------------------------------------------
__global__ __launch_bounds__(256) void build_cats(
    const float* __restrict__ Bre, const float* __restrict__ Bim,
    const float* __restrict__ gre, const float* __restrict__ gim,
    const float* __restrict__ Cre, const float* __restrict__ Cim,
    u16* __restrict__ Bcat, u16* __restrict__ Ccat)
{
    int b = blockIdx.x;
    if (b < 1024) {
        int idx = b * 256 + threadIdx.x;    // p*H + h
        int p = idx >> 9, h = idx & 511;
        float br = Bre[idx], bi = Bim[idx];
        float gr = gre[p], gi = gim[p];
        Bcat[(size_t)p * 512 + h]         = f2h(gr * br - gi * bi);
        Bcat[(size_t)(512 + p) * 512 + h] = f2h(gr * bi + gi * br);
    } else {
        int idx = (b - 1024) * 256 + threadIdx.x;   // h*P + p
        int h = idx >> 9, p = idx & 511;
        size_t row = (size_t)h * 1024;
        Ccat[row + p]       = f2h(Cre[idx]);
        Ccat[row + 512 + p] = f2h(-Cim[idx]);
    }
}

// ---------------------------------------------------------------------------
// MFMA GEMM, 128x128 tile, BK=64, 4 waves (each 64x64), global_load_lds
// staging, XOR-swizzled source / ds_read pair.
// MODE 0 (Bu GEMM): writes Bu fp16 (re|im split at col 512) AND fused
//   weighted chunk-sum partials from the fp32 accumulators:
//   Rwr[c][p]=sum_k wr*Bu_re, Rwi=sum_k wi*Bu_re (re-cols);
//   Iwr/Iwi likewise from im-cols; w_k = lambda_p^(31-k).
// MODE 1 (y GEMM): out fp32 = acc + D[col]*uh[row,col].
// __launch_bounds__(256,2): 256-reg budget. (256,4) caps at 128 and SPILLS —
// round-3 regression: +183MB scratch writes/dispatch, GEMM 64->118us.
// ---------------------------------------------------------------------------
template<int KTOT, int NBN, int MODE>
__global__ __launch_bounds__(256, 2) void gemm_mfma(
    const u16* __restrict__ A0, const u16* __restrict__ A1,
    const u16* __restrict__ Bmat,
    void* __restrict__ O0v, void* __restrict__ O1v,
    const float* __restrict__ Dvec, const u16* __restrict__ uIn,
    const float* __restrict__ powr, const float* __restrict__ powi,
    float* __restrict__ Rwr, float* __restrict__ Rwi,
    float* __restrict__ Iwr, float* __restrict__ Iwi)
{
    __shared__ u16 Als[128 * 64];
    __shared__ u16 Bls[128 * 64];

    const u16* Aseg[2] = {A0, A1};

    // XCD-chunked block mapping: same-M blocks land on the same XCD (b%8).
    int b = blockIdx.x;
    int m = (b & 7) * 16 + b / (8 * NBN);
    int n = (b >> 3) & (NBN - 1);
    int m0 = m * 128, n0 = n * 128;

    int tid = threadIdx.x;
    int w = tid >> 6, lane = tid & 63;
    int wm = w >> 1, wn = w & 1;

    f32x4 acc[4][4];
    #pragma unroll
    for (int i = 0; i < 4; ++i)
        #pragma unroll
        for (int j = 0; j < 4; ++j) acc[i][j] = (f32x4)0.f;

    int lr8  = lane >> 3;   // 0..7
    int slin = lane & 7;    // linear 16B slot this lane writes

    char* AlsB = (char*)&Als[0];
    char* BlsB = (char*)&Bls[0];

    const int NSEG = KTOT / 512;
    #pragma unroll
    for (int seg = 0; seg < NSEG; ++seg) {
        const u16* Ap = Aseg[seg];
        for (int k8 = 0; k8 < 8; ++k8) {
            int ko = k8 * 64;           // K offset within segment (elements)
            int kB = seg * 512 + ko;    // K offset within full KTOT (for B)

            __syncthreads();            // previous tile fully consumed
            #pragma unroll
            for (int c = 0; c < 4; ++c) {
                int sidx = w * 4 + c;           // 16 wave-issues cover 16KB
                int r = sidx * 8 + lr8;         // tile row this lane feeds
                int g = slin ^ (r & 7);         // pre-swizzled source slot
                const u16* ga = Ap + (size_t)(m0 + r) * 512 + ko + g * 8;
                gload16(ga, AlsB + sidx * 1024);
                const u16* gb = Bmat + (size_t)(n0 + r) * KTOT + kB + g * 8;
                gload16(gb, BlsB + sidx * 1024);
            }
            asm volatile("s_waitcnt vmcnt(0)" ::: "memory");
            __syncthreads();            // staged tile visible

            f16x8 a[4][2], bf[4][2];
            #pragma unroll
            for (int mm = 0; mm < 4; ++mm)
                #pragma unroll
                for (int kk = 0; kk < 2; ++kk) {
                    int row = wm * 64 + mm * 16 + (lane & 15);
                    int sl  = kk * 4 + (lane >> 4);
                    int off = row * 128 + ((sl ^ (lane & 7)) << 4);
                    a[mm][kk] = *(const f16x8*)(AlsB + off);
                }
            #pragma unroll
            for (int nn = 0; nn < 4; ++nn)
                #pragma unroll
                for (int kk = 0; kk < 2; ++kk) {
                    int row = wn * 64 + nn * 16 + (lane & 15);
                    int sl  = kk * 4 + (lane >> 4);
                    int off = row * 128 + ((sl ^ (lane & 7)) << 4);
                    bf[nn][kk] = *(const f16x8*)(BlsB + off);
                }
            #pragma unroll
            for (int mm = 0; mm < 4; ++mm)
                #pragma unroll
                for (int nn = 0; nn < 4; ++nn) {
                    acc[mm][nn] = mfma_f16(a[mm][0], bf[nn][0], acc[mm][nn]);
                    acc[mm][nn] = mfma_f16(a[mm][1], bf[nn][1], acc[mm][nn]);
                }
        }
    }

    // epilogue: C/D layout col = lane&15, row = (lane>>4)*4 + reg  [m89]
    int colb = n0 + wn * 64;
    int rowb = m0 + wm * 64;
    #pragma unroll
    for (int mm = 0; mm < 4; ++mm)
        #pragma unroll
        for (int nn = 0; nn < 4; ++nn) {
            f32x4 v = acc[mm][nn];
            int col = colb + nn * 16 + (lane & 15);
            #pragma unroll
            for (int j = 0; j < 4; ++j) {
                int row = rowb + mm * 16 + (lane >> 4) * 4 + j;
                if constexpr (MODE == 0) {
                    size_t oidx = (size_t)row * 512 + (col & 511);
                    u16 hv = f2h(v[j]);
                    if (col < 512) ((u16*)O0v)[oidx] = hv;
                    else           ((u16*)O1v)[oidx] = hv;
                } else {
                    size_t oidx = (size_t)row * 512 + col;
                    ((float*)O0v)[oidx] = v[j] + Dvec[col] * h2f(uIn[oidx]);
                }
            }
        }

    if constexpr (MODE == 0) {
        // fused weighted chunk sums. k for acc[mm] depends only on (mm&1, j),
        // so the (e,p) weight is shared by ch=mm>>1 in {0,1}: load once,
        // apply to both chunks (64 loads/lane, was 128).
        float swr[2][4] = {{0.f}};
        float swi[2][4] = {{0.f}};
        #pragma unroll
        for (int h = 0; h < 2; ++h)
            #pragma unroll
            for (int j = 0; j < 4; ++j) {
                int k = h * 16 + (lane >> 4) * 4 + j;    // 0..31
                int e = (T_CH - 1) - k;
                #pragma unroll
                for (int nn = 0; nn < 4; ++nn) {
                    int p = (colb + nn * 16 + (lane & 15)) & 511;
                    float wr = powr[(size_t)e * 512 + p];
                    float wi = powi[(size_t)e * 512 + p];
                    swr[0][nn] = fmaf(wr, acc[h][nn][j],     swr[0][nn]);
                    swi[0][nn] = fmaf(wi, acc[h][nn][j],     swi[0][nn]);
                    swr[1][nn] = fmaf(wr, acc[2 + h][nn][j], swr[1][nn]);
                    swi[1][nn] = fmaf(wi, acc[2 + h][nn][j], swi[1][nn]);
                }
            }
        #pragma unroll
        for (int ch = 0; ch < 2; ++ch)
            #pragma unroll
            for (int nn = 0; nn < 4; ++nn) {
                float a2 = swr[ch][nn];
                a2 += __shfl_xor(a2, 16); a2 += __shfl_xor(a2, 32);
                swr[ch][nn] = a2;
                float b2 = swi[ch][nn];
                b2 += __shfl_xor(b2, 16); b2 += __shfl_xor(b2, 32);
                swi[ch][nn] = b2;
            }
        if (lane < 16) {
            #pragma unroll
            for (int ch = 0; ch < 2; ++ch) {
                int c = (m0 >> 5) + wm * 2 + ch;   // global chunk index
                #pragma unroll
                for (int nn = 0; nn < 4; ++nn) {
                    int col = colb + nn * 16 + lane;
                    int p = col & 511;
                    size_t pidx = (size_t)c * 512 + p;
                    if (col < 512) { Rwr[pidx] = swr[ch][nn]; Rwi[pidx] = swi[ch][nn]; }
                    else           { Iwr[pidx] = swr[ch][nn]; Iwi[pidx] = swi[ch][nn]; }
                }
            }
        }
    }
}

// ---------------------------------------------------------------------------
// scan chunks: exclusive scan across 512 chunk aggregates with factor
// lambda^32. Combines the 4 gemm partials on the fly:
//   s_re = Rwr - Iwi ; s_im = Rwi + Iwr.
// 8 blocks x 64 threads so L2 traffic isn't funneled through one CU.
// ---------------------------------------------------------------------------
__global__ __launch_bounds__(64) void scan_chunks(
    const float* __restrict__ Rwr, const float* __restrict__ Rwi,
    const float* __restrict__ Iwr, const float* __restrict__ Iwi,
    const float* __restrict__ powr, const float* __restrict__ powi,
    float* __restrict__ carr, float* __restrict__ cari)
{
    int p = blockIdx.x * 64 + threadIdx.x;
    float ar = powr[(size_t)T_CH * P_DIM + p];   // lambda^32
    float ai = powi[(size_t)T_CH * P_DIM + p];
    float sr = 0.f, si = 0.f;
    #pragma unroll 8
    for (int c = 0; c < NC; ++c) {
        size_t idx = (size_t)c * P_DIM + p;
        carr[idx] = sr; cari[idx] = si;
        float vre = Rwr[idx] - Iwi[idx];
        float vim = Rwi[idx] + Iwr[idx];
        float nr = fmaf(ar, sr, fmaf(-ai, si, vre));
        float ni = fmaf(ar, si, fmaf( ai, sr, vim));
        sr = nr; si = ni;
    }
}

// ---------------------------------------------------------------------------
// scan fix: local recurrence seeded with carry; emit x as fp16.
// One WAVE per chunk, 8 channels/lane: u16x8 (16B/lane) coalesced loads and
// stores — 8x fewer VMEM instructions than the scalar-2B round-5 version
// (Guideline 13). 512 blocks x 64 threads = 2 waves/CU across all CUs.
// ---------------------------------------------------------------------------
__global__ __launch_bounds__(64) void scan_fix(
    const u16* __restrict__ burh, const u16* __restrict__ buih,
    const float* __restrict__ lbr, const float* __restrict__ lbi,
    const float* __restrict__ carr, const float* __restrict__ cari,
    u16* __restrict__ xrh, u16* __restrict__ xih)
{
    int c = blockIdx.x;               // chunk
    int lane = threadIdx.x;           // 0..63
    int p0 = lane * 8;
    float lr[8], li[8], xr[8], xi[8];
    #pragma unroll
    for (int j = 0; j < 8; j += 4) {
        float4 vr = *(const float4*)(lbr + p0 + j);
        float4 vi = *(const float4*)(lbi + p0 + j);
        lr[j] = vr.x; lr[j+1] = vr.y; lr[j+2] = vr.z; lr[j+3] = vr.w;
        li[j] = vi.x; li[j+1] = vi.y; li[j+2] = vi.z; li[j+3] = vi.w;
        float4 cr = *(const float4*)(carr + (size_t)c * P_DIM + p0 + j);
        float4 ci = *(const float4*)(cari + (size_t)c * P_DIM + p0 + j);
        xr[j] = cr.x; xr[j+1] = cr.y; xr[j+2] = cr.z; xr[j+3] = cr.w;
        xi[j] = ci.x; xi[j+1] = ci.y; xi[j+2] = ci.z; xi[j+3] = ci.w;
    }
    size_t base = (size_t)c * T_CH * P_DIM + p0;
    #pragma unroll 4
    for (int k = 0; k < T_CH; ++k) {
        size_t idx = base + (size_t)k * P_DIM;
        u16x8 br8 = *(const u16x8*)(burh + idx);
        u16x8 bi8 = *(const u16x8*)(buih + idx);
        u16x8 or8, oi8;
        #pragma unroll
        for (int j = 0; j < 8; ++j) {
            float br = h2f(br8[j]), bi = h2f(bi8[j]);
            float nr = fmaf(lr[j], xr[j], fmaf(-li[j], xi[j], br));
            float ni = fmaf(lr[j], xi[j], fmaf( li[j], xr[j], bi));
            xr[j] = nr; xi[j] = ni;
            or8[j] = f2h(nr); oi8[j] = f2h(ni);
        }
        *(u16x8*)(xrh + idx) = or8;
        *(u16x8*)(xih + idx) = oi8;
    }
}

// ---------------------------------------------------------------------------
extern "C" void kernel_launch(void* const* d_in, const int* in_sizes, int n_in,
                              void* d_out, int out_size, void* d_ws, size_t ws_size,
                              hipStream_t stream)
{
    const float* u        = (const float*)d_in[0];
    const float* Lre      = (const float*)d_in[1];
    const float* Lim      = (const float*)d_in[2];
    const float* Bre      = (const float*)d_in[3];
    const float* Bim      = (const float*)d_in[4];
    const float* Cre      = (const float*)d_in[5];
    const float* Cim      = (const float*)d_in[6];
    const float* D        = (const float*)d_in[7];
    const float* log_step = (const float*)d_in[8];
    float* out = (float*)d_out;

    // workspace layout (bytes)
    char* w8 = (char*)d_ws;
    u16*   burh = (u16*)(w8);                                // 16 MB
    u16*   buih = (u16*)(w8 + 16777216);                     // 16 MB
    u16*   xrh  = (u16*)(w8 + 33554432);                     // 16 MB
    u16*   xih  = (u16*)(w8 + 50331648);                     // 16 MB
    u16*   uh   = (u16*)(w8 + 67108864);                     // 16 MB
    u16*   Bcat = (u16*)(w8 + 83886080);                     // 1 MB
    u16*   Ccat = (u16*)(w8 + 84934656);                     // 1 MB
    float* Rwr  = (float*)(w8 + 85983232);                   // 1 MB (NC*P fp32)
    float* Rwi  = (float*)(w8 + 87031808);
    float* Iwr  = (float*)(w8 + 88080384);
    float* Iwi  = (float*)(w8 + 89128960);
    float* carr = (float*)(w8 + 90177536);                   // 1 MB
    float* cari = (float*)(w8 + 91226112);
    float* powr = (float*)(w8 + 92274688);                   // 33*512*4
    float* powi = (float*)(w8 + 92342272);
    float* lbr  = (float*)(w8 + 92409856);                   // small
    float* lbi  = lbr + P_DIM;
    float* gre  = lbi + P_DIM;
    float* gim  = gre + P_DIM;

    prep_kernel<<<1, P_DIM, 0, stream>>>(Lre, Lim, log_step, lbr, lbi, gre, gim, powr, powi);
    build_cats<<<2048, 256, 0, stream>>>(Bre, Bim, gre, gim, Cre, Cim, Bcat, Ccat);
    convert_u<<<(int)(LH / 2048), 256, 0, stream>>>(u, uh);

    // Bu GEMM (+fused chunk-sum partials): A = uh, B = Bcat (1024 x 512)
    gemm_mfma<512, 8, 0><<<1024, 256, 0, stream>>>(
        uh, uh, Bcat, burh, buih, nullptr, nullptr,
        powr, powi, Rwr, Rwi, Iwr, Iwi);

    scan_chunks<<<8, 64, 0, stream>>>(Rwr, Rwi, Iwr, Iwi, powr, powi, carr, cari);
    scan_fix<<<NC, 64, 0, stream>>>(burh, buih, lbr, lbi, carr, cari, xrh, xih);

    // y GEMM: A segs [xr | xi] (fp16), B = Ccat (512 x 1024) -> out (+D*uh)
    gemm_mfma<1024, 4, 1><<<512, 256, 0, stream>>>(
        xrh, xih, Ccat, out, nullptr, D, uh,
        nullptr, nullptr, nullptr, nullptr, nullptr, nullptr);
}

// Round 7
// 121.914 us; speedup vs baseline: 1.0714x; 1.0710x over previous
//
#include <hip/hip_runtime.h>
#include <stdint.h>

#define L_DIM 16384
#define H_DIM 512
#define P_DIM 512
#define T_CH  32
#define NC    (L_DIM / T_CH)      // 512 chunks
#define LP    ((size_t)L_DIM * P_DIM)
#define LH    ((size_t)L_DIM * H_DIM)

typedef unsigned short u16;
typedef __attribute__((ext_vector_type(8))) _Float16 f16x8;  // 8 fp16 = 4 VGPRs
typedef __attribute__((ext_vector_type(4))) float f32x4;
typedef __attribute__((ext_vector_type(8))) unsigned short u16x8;

// ---- fp16 helpers ----------------------------------------------------------
__device__ __forceinline__ u16 f2h(float x) {
    _Float16 h = (_Float16)x;            // RTNE
    return __builtin_bit_cast(u16, h);
}
__device__ __forceinline__ float h2f(u16 h) {
    return (float)__builtin_bit_cast(_Float16, h);
}

// ---- async global->LDS, 16B per lane, wave-uniform LDS base ----------------
__device__ __forceinline__ void gload16(const void* g, void* lds) {
    __builtin_amdgcn_global_load_lds(
        (const __attribute__((address_space(1))) void*)g,
        (__attribute__((address_space(3))) void*)(uintptr_t)lds,
        16, 0, 0);
}

__device__ __forceinline__ f32x4 mfma_f16(f16x8 a, f16x8 b, f32x4 c) {
    return __builtin_amdgcn_mfma_f32_16x16x32_f16(a, b, c, 0, 0, 0);
}

// ---------------------------------------------------------------------------
// front kernel: one dispatch replacing prep + build_bcat + build_ccat +
// convert_u (all mutually independent; B/C builds recompute gamma per
// element from raw inputs so nothing depends on the prep part).
//   blocks [0, 4096)      : convert u (L,H) fp32 -> fp16, 8 elems/thread
//   blocks [4096, 5120)   : Bcat (1024 x 512) fp16 = [Re(gamma*B); Im(gamma*B)]
//   blocks [5120, 6144)   : Ccat (512 x 1024) fp16 = [Cre | -Cim] per row
//   block  6144           : lambda_bar + power table lambda^k (k=0..32)
// ---------------------------------------------------------------------------
__device__ __forceinline__ void zoh_lambda(
    const float* Lre, const float* Lim, const float* log_step, int p,
    float& lr, float& li)
{
    float st = expf(log_step[p]);
    float ar = Lre[p] * st, ai = Lim[p] * st;
    float er = expf(ar);
    lr = er * cosf(ai);
    li = er * sinf(ai);
}

__global__ __launch_bounds__(256) void front_kernel(
    const float* __restrict__ u,
    const float* __restrict__ Lre, const float* __restrict__ Lim,
    const float* __restrict__ log_step,
    const float* __restrict__ Bre, const float* __restrict__ Bim,
    const float* __restrict__ Cre, const float* __restrict__ Cim,
    u16* __restrict__ uh, u16* __restrict__ Bcat, u16* __restrict__ Ccat,
    float* __restrict__ lbr, float* __restrict__ lbi,
    float* __restrict__ powr, float* __restrict__ powi)
{
    int b = blockIdx.x;
    if (b < 4096) {
        size_t i = ((size_t)b * 256 + threadIdx.x) * 8;
        float4 v0 = *(const float4*)(u + i);
        float4 v1 = *(const float4*)(u + i + 4);
        u16x8 h;
        h[0] = f2h(v0.x); h[1] = f2h(v0.y); h[2] = f2h(v0.z); h[3] = f2h(v0.w);
        h[4] = f2h(v1.x); h[5] = f2h(v1.y); h[6] = f2h(v1.z); h[7] = f2h(v1.w);
        *(u16x8*)(uh + i) = h;
    } else if (b < 5120) {
        int idx = (b - 4096) * 256 + threadIdx.x;   // p*H + h
        int p = idx >> 9, h = idx & 511;
        float lr, li;
        zoh_lambda(Lre, Lim, log_step, p, lr, li);
        float den = Lre[p] * Lre[p] + Lim[p] * Lim[p];
        float x = lr - 1.0f, y = li;
        float gr = (x * Lre[p] + y * Lim[p]) / den;
        float gi = (y * Lre[p] - x * Lim[p]) / den;
        float br = Bre[idx], bi = Bim[idx];
        Bcat[(size_t)p * 512 + h]         = f2h(gr * br - gi * bi);
        Bcat[(size_t)(512 + p) * 512 + h] = f2h(gr * bi + gi * br);
    } else if (b < 6144) {
        int idx = (b - 5120) * 256 + threadIdx.x;   // h*P + p
        int h = idx >> 9, p = idx & 511;
        size_t row = (size_t)h * 1024;
        Ccat[row + p]       = f2h(Cre[idx]);
        Ccat[row + 512 + p] = f2h(-Cim[idx]);
    } else {
        #pragma unroll
        for (int t = 0; t < 2; ++t) {
            int p = threadIdx.x + t * 256;
            float lr, li;
            zoh_lambda(Lre, Lim, log_step, p, lr, li);
            lbr[p] = lr; lbi[p] = li;
            float pr = 1.f, pi2 = 0.f;
            powr[p] = 1.f; powi[p] = 0.f;
            for (int k = 1; k <= T_CH; ++k) {
                float nr = pr * lr - pi2 * li;
                float ni = pr * li + pi2 * lr;
                pr = nr; pi2 = ni;
                powr[(size_t)k * P_DIM + p] = pr;
                powi[(size_t)k * P_DIM + p] = pi2;
            }
        }
    }
}

// ---------------------------------------------------------------------------
// MFMA GEMM, 128x128 tile, BK=64, 4 waves (each 64x64), global_load_lds
// staging, XOR-swizzled source / ds_read pair.
// MODE 0 (Bu GEMM): writes Bu fp16 (re|im split at col 512) AND fused
//   weighted chunk-sum partials from the fp32 accumulators:
//   Rwr[c][p]=sum_k wr*Bu_re, Rwi=sum_k wi*Bu_re (re-cols);
//   Iwr/Iwi likewise from im-cols; w_k = lambda_p^(31-k).
// MODE 1 (y GEMM): out fp32 = acc + D[col]*uh[row,col].
// __launch_bounds__(256,2): 256-reg budget. (256,4) caps at 128 and SPILLS —
// round-3 regression: +183MB scratch writes/dispatch, GEMM 64->118us.
// ---------------------------------------------------------------------------
template<int KTOT, int NBN, int MODE>
__global__ __launch_bounds__(256, 2) void gemm_mfma(
    const u16* __restrict__ A0, const u16* __restrict__ A1,
    const u16* __restrict__ Bmat,
    void* __restrict__ O0v, void* __restrict__ O1v,
    const float* __restrict__ Dvec, const u16* __restrict__ uIn,
    const float* __restrict__ powr, const float* __restrict__ powi,
    float* __restrict__ Rwr, float* __restrict__ Rwi,
    float* __restrict__ Iwr, float* __restrict__ Iwi)
{
    __shared__ u16 Als[128 * 64];
    __shared__ u16 Bls[128 * 64];

    const u16* Aseg[2] = {A0, A1};

    // XCD-chunked block mapping: same-M blocks land on the same XCD (b%8).
    int b = blockIdx.x;
    int m = (b & 7) * 16 + b / (8 * NBN);
    int n = (b >> 3) & (NBN - 1);
    int m0 = m * 128, n0 = n * 128;

    int tid = threadIdx.x;
    int w = tid >> 6, lane = tid & 63;
    int wm = w >> 1, wn = w & 1;

    f32x4 acc[4][4];
    #pragma unroll
    for (int i = 0; i < 4; ++i)
        #pragma unroll
        for (int j = 0; j < 4; ++j) acc[i][j] = (f32x4)0.f;

    int lr8  = lane >> 3;   // 0..7
    int slin = lane & 7;    // linear 16B slot this lane writes

    char* AlsB = (char*)&Als[0];
    char* BlsB = (char*)&Bls[0];

    const int NSEG = KTOT / 512;
    #pragma unroll
    for (int seg = 0; seg < NSEG; ++seg) {
        const u16* Ap = Aseg[seg];
        for (int k8 = 0; k8 < 8; ++k8) {
            int ko = k8 * 64;           // K offset within segment (elements)
            int kB = seg * 512 + ko;    // K offset within full KTOT (for B)

            __syncthreads();            // previous tile fully consumed
            #pragma unroll
            for (int c = 0; c < 4; ++c) {
                int sidx = w * 4 + c;           // 16 wave-issues cover 16KB
                int r = sidx * 8 + lr8;         // tile row this lane feeds
                int g = slin ^ (r & 7);         // pre-swizzled source slot
                const u16* ga = Ap + (size_t)(m0 + r) * 512 + ko + g * 8;
                gload16(ga, AlsB + sidx * 1024);
                const u16* gb = Bmat + (size_t)(n0 + r) * KTOT + kB + g * 8;
                gload16(gb, BlsB + sidx * 1024);
            }
            asm volatile("s_waitcnt vmcnt(0)" ::: "memory");
            __syncthreads();            // staged tile visible

            f16x8 a[4][2], bf[4][2];
            #pragma unroll
            for (int mm = 0; mm < 4; ++mm)
                #pragma unroll
                for (int kk = 0; kk < 2; ++kk) {
                    int row = wm * 64 + mm * 16 + (lane & 15);
                    int sl  = kk * 4 + (lane >> 4);
                    int off = row * 128 + ((sl ^ (lane & 7)) << 4);
                    a[mm][kk] = *(const f16x8*)(AlsB + off);
                }
            #pragma unroll
            for (int nn = 0; nn < 4; ++nn)
                #pragma unroll
                for (int kk = 0; kk < 2; ++kk) {
                    int row = wn * 64 + nn * 16 + (lane & 15);
                    int sl  = kk * 4 + (lane >> 4);
                    int off = row * 128 + ((sl ^ (lane & 7)) << 4);
                    bf[nn][kk] = *(const f16x8*)(BlsB + off);
                }
            #pragma unroll
            for (int mm = 0; mm < 4; ++mm)
                #pragma unroll
                for (int nn = 0; nn < 4; ++nn) {
                    acc[mm][nn] = mfma_f16(a[mm][0], bf[nn][0], acc[mm][nn]);
                    acc[mm][nn] = mfma_f16(a[mm][1], bf[nn][1], acc[mm][nn]);
                }
        }
    }

    // epilogue: C/D layout col = lane&15, row = (lane>>4)*4 + reg  [m89]
    int colb = n0 + wn * 64;
    int rowb = m0 + wm * 64;
    #pragma unroll
    for (int mm = 0; mm < 4; ++mm)
        #pragma unroll
        for (int nn = 0; nn < 4; ++nn) {
            f32x4 v = acc[mm][nn];
            int col = colb + nn * 16 + (lane & 15);
            #pragma unroll
            for (int j = 0; j < 4; ++j) {
                int row = rowb + mm * 16 + (lane >> 4) * 4 + j;
                if constexpr (MODE == 0) {
                    size_t oidx = (size_t)row * 512 + (col & 511);
                    u16 hv = f2h(v[j]);
                    if (col < 512) ((u16*)O0v)[oidx] = hv;
                    else           ((u16*)O1v)[oidx] = hv;
                } else {
                    size_t oidx = (size_t)row * 512 + col;
                    ((float*)O0v)[oidx] = v[j] + Dvec[col] * h2f(uIn[oidx]);
                }
            }
        }

    if constexpr (MODE == 0) {
        // fused weighted chunk sums. k for acc[mm] depends only on (mm&1, j),
        // so the (e,p) weight is shared by ch=mm>>1 in {0,1}: load once,
        // apply to both chunks (64 loads/lane).
        float swr[2][4] = {{0.f}};
        float swi[2][4] = {{0.f}};
        #pragma unroll
        for (int h = 0; h < 2; ++h)
            #pragma unroll
            for (int j = 0; j < 4; ++j) {
                int k = h * 16 + (lane >> 4) * 4 + j;    // 0..31
                int e = (T_CH - 1) - k;
                #pragma unroll
                for (int nn = 0; nn < 4; ++nn) {
                    int p = (colb + nn * 16 + (lane & 15)) & 511;
                    float wr = powr[(size_t)e * 512 + p];
                    float wi = powi[(size_t)e * 512 + p];
                    swr[0][nn] = fmaf(wr, acc[h][nn][j],     swr[0][nn]);
                    swi[0][nn] = fmaf(wi, acc[h][nn][j],     swi[0][nn]);
                    swr[1][nn] = fmaf(wr, acc[2 + h][nn][j], swr[1][nn]);
                    swi[1][nn] = fmaf(wi, acc[2 + h][nn][j], swi[1][nn]);
                }
            }
        #pragma unroll
        for (int ch = 0; ch < 2; ++ch)
            #pragma unroll
            for (int nn = 0; nn < 4; ++nn) {
                float a2 = swr[ch][nn];
                a2 += __shfl_xor(a2, 16); a2 += __shfl_xor(a2, 32);
                swr[ch][nn] = a2;
                float b2 = swi[ch][nn];
                b2 += __shfl_xor(b2, 16); b2 += __shfl_xor(b2, 32);
                swi[ch][nn] = b2;
            }
        if (lane < 16) {
            #pragma unroll
            for (int ch = 0; ch < 2; ++ch) {
                int c = (m0 >> 5) + wm * 2 + ch;   // global chunk index
                #pragma unroll
                for (int nn = 0; nn < 4; ++nn) {
                    int col = colb + nn * 16 + lane;
                    int p = col & 511;
                    size_t pidx = (size_t)c * 512 + p;
                    if (col < 512) { Rwr[pidx] = swr[ch][nn]; Rwi[pidx] = swi[ch][nn]; }
                    else           { Iwr[pidx] = swr[ch][nn]; Iwi[pidx] = swi[ch][nn]; }
                }
            }
        }
    }
}

// ---------------------------------------------------------------------------
// scan chunks: exclusive scan across 512 chunk aggregates with factor
// lambda^32. Combines the 4 gemm partials on the fly:
//   s_re = Rwr - Iwi ; s_im = Rwi + Iwr.
// 8 blocks x 64 threads so L2 traffic isn't funneled through one CU.
// ---------------------------------------------------------------------------
__global__ __launch_bounds__(64) void scan_chunks(
    const float* __restrict__ Rwr, const float* __restrict__ Rwi,
    const float* __restrict__ Iwr, const float* __restrict__ Iwi,
    const float* __restrict__ powr, const float* __restrict__ powi,
    float* __restrict__ carr, float* __restrict__ cari)
{
    int p = blockIdx.x * 64 + threadIdx.x;
    float ar = powr[(size_t)T_CH * P_DIM + p];   // lambda^32
    float ai = powi[(size_t)T_CH * P_DIM + p];
    float sr = 0.f, si = 0.f;
    #pragma unroll 8
    for (int c = 0; c < NC; ++c) {
        size_t idx = (size_t)c * P_DIM + p;
        carr[idx] = sr; cari[idx] = si;
        float vre = Rwr[idx] - Iwi[idx];
        float vim = Rwi[idx] + Iwr[idx];
        float nr = fmaf(ar, sr, fmaf(-ai, si, vre));
        float ni = fmaf(ar, si, fmaf( ai, sr, vim));
        sr = nr; si = ni;
    }
}

// ---------------------------------------------------------------------------
// scan fix: local recurrence seeded with carry; emit x as fp16.
// Thread-per-(chunk,channel): 512 blocks x 512 threads = 16 waves/CU.
// NOTE: the "vectorized" wave-per-chunk variant (64-thr blocks, u16x8) was
// a −12us REGRESSION (round 6): 2 waves/CU cannot hide load latency —
// TLP beats per-instruction width here (scalar 2B loads still coalesce
// to 128B/wave). Do not re-vectorize without raising waves/CU.
// ---------------------------------------------------------------------------
__global__ __launch_bounds__(P_DIM) void scan_fix(
    const u16* __restrict__ burh, const u16* __restrict__ buih,
    const float* __restrict__ lbr, const float* __restrict__ lbi,
    const float* __restrict__ carr, const float* __restrict__ cari,
    u16* __restrict__ xrh, u16* __restrict__ xih)
{
    int p = threadIdx.x;
    int c = blockIdx.x;
    float lr = lbr[p], li = lbi[p];
    float xr = carr[(size_t)c * P_DIM + p];
    float xi = cari[(size_t)c * P_DIM + p];
    size_t base = (size_t)c * T_CH * P_DIM + p;
    #pragma unroll 4
    for (int k = 0; k < T_CH; ++k) {
        size_t idx = base + (size_t)k * P_DIM;
        float br = h2f(burh[idx]), bi = h2f(buih[idx]);
        float nr = fmaf(lr, xr, fmaf(-li, xi, br));
        float ni = fmaf(lr, xi, fmaf( li, xr, bi));
        xr = nr; xi = ni;
        xrh[idx] = f2h(xr);
        xih[idx] = f2h(xi);
    }
}

// ---------------------------------------------------------------------------
extern "C" void kernel_launch(void* const* d_in, const int* in_sizes, int n_in,
                              void* d_out, int out_size, void* d_ws, size_t ws_size,
                              hipStream_t stream)
{
    const float* u        = (const float*)d_in[0];
    const float* Lre      = (const float*)d_in[1];
    const float* Lim      = (const float*)d_in[2];
    const float* Bre      = (const float*)d_in[3];
    const float* Bim      = (const float*)d_in[4];
    const float* Cre      = (const float*)d_in[5];
    const float* Cim      = (const float*)d_in[6];
    const float* D        = (const float*)d_in[7];
    const float* log_step = (const float*)d_in[8];
    float* out = (float*)d_out;

    // workspace layout (bytes)
    char* w8 = (char*)d_ws;
    u16*   burh = (u16*)(w8);                                // 16 MB
    u16*   buih = (u16*)(w8 + 16777216);                     // 16 MB
    u16*   xrh  = (u16*)(w8 + 33554432);                     // 16 MB
    u16*   xih  = (u16*)(w8 + 50331648);                     // 16 MB
    u16*   uh   = (u16*)(w8 + 67108864);                     // 16 MB
    u16*   Bcat = (u16*)(w8 + 83886080);                     // 1 MB
    u16*   Ccat = (u16*)(w8 + 84934656);                     // 1 MB
    float* Rwr  = (float*)(w8 + 85983232);                   // 1 MB (NC*P fp32)
    float* Rwi  = (float*)(w8 + 87031808);
    float* Iwr  = (float*)(w8 + 88080384);
    float* Iwi  = (float*)(w8 + 89128960);
    float* carr = (float*)(w8 + 90177536);                   // 1 MB
    float* cari = (float*)(w8 + 91226112);
    float* powr = (float*)(w8 + 92274688);                   // 33*512*4
    float* powi = (float*)(w8 + 92342272);
    float* lbr  = (float*)(w8 + 92409856);                   // small
    float* lbi  = lbr + P_DIM;

    // one front dispatch: convert_u (4096 blk) + Bcat (1024) + Ccat (1024)
    // + lambda/power prep (1 blk)
    front_kernel<<<6145, 256, 0, stream>>>(
        u, Lre, Lim, log_step, Bre, Bim, Cre, Cim,
        uh, Bcat, Ccat, lbr, lbi, powr, powi);

    // Bu GEMM (+fused chunk-sum partials): A = uh, B = Bcat (1024 x 512)
    gemm_mfma<512, 8, 0><<<1024, 256, 0, stream>>>(
        uh, uh, Bcat, burh, buih, nullptr, nullptr,
        powr, powi, Rwr, Rwi, Iwr, Iwi);

    scan_chunks<<<8, 64, 0, stream>>>(Rwr, Rwi, Iwr, Iwi, powr, powi, carr, cari);
    scan_fix<<<NC, P_DIM, 0, stream>>>(burh, buih, lbr, lbi, carr, cari, xrh, xih);

    // y GEMM: A segs [xr | xi] (fp16), B = Ccat (512 x 1024) -> out (+D*uh)
    gemm_mfma<1024, 4, 1><<<512, 256, 0, stream>>>(
        xrh, xih, Ccat, out, nullptr, D, uh,
        nullptr, nullptr, nullptr, nullptr, nullptr, nullptr);
}